// Round 3
// baseline (812.547 us; speedup 1.0000x reference)
//
#include <hip/hip_runtime.h>

// ESIM layer: out = softmax((x@W + b) @ y^T) @ y
// B=64, Sx=Sy=512, D=1024, fp32 in/out.
//
// Round-4 changes vs 703µs (attn latency-bound: vmcnt(0) drains HBM A-loads
// with only ~320cyc cover; phase-2 40cyc cover):
//  * attn phase 0: full unroll, counted s_waitcnt vmcnt(8) (never 0 mid-loop),
//    A-prefetch depth 2 (~2-iter ≈ 800cyc cover for HBM), S depth 1.
//  * proj slot layout: h/l interleaved per 8-half group (h@g*32B, l@+16) so
//    attn A-loads touch half the cache lines.
//  * attn phase 2: Yt double-buffer + counted vmcnt, kk-unrolled; Pbuf [64][512]
//    chunk-XOR swizzle; LDS = 81920B exactly (2 blocks/CU), Red aliased in Yt1.
//  * proj: LDS dbuf (48KB, 3 blocks/CU), ONE barrier/K-step, stage-early.

typedef float  f32x4  __attribute__((ext_vector_type(4)));
typedef _Float16 f16x8 __attribute__((ext_vector_type(8)));
typedef _Float16 f16x4 __attribute__((ext_vector_type(4)));
typedef __bf16 bf16x8 __attribute__((ext_vector_type(8)));
typedef __bf16 bf16x4 __attribute__((ext_vector_type(4)));

#define MFMA_F16(a, b, c)  __builtin_amdgcn_mfma_f32_16x16x32_f16((a), (b), (c), 0, 0, 0)
#define MFMA_BF16(a, b, c) __builtin_amdgcn_mfma_f32_16x16x32_bf16((a), (b), (c), 0, 0, 0)

#define WAIT_VM(N)  do { asm volatile("s_waitcnt vmcnt(" #N ")" ::: "memory"); \
                         __builtin_amdgcn_sched_barrier(0); } while (0)
#define WAIT_LGKM0() do { asm volatile("s_waitcnt lgkmcnt(0)" ::: "memory"); \
                          __builtin_amdgcn_sched_barrier(0); } while (0)
#define SB0() __builtin_amdgcn_sched_barrier(0)

__device__ __forceinline__ void async16(const void* g, void* lds) {
    __builtin_amdgcn_global_load_lds(
        (const __attribute__((address_space(1))) unsigned int*)g,
        (__attribute__((address_space(3))) unsigned int*)lds, 16, 0, 0);
}

// ========================= prep kernels =====================================

// fused: y fp32 -> yf fp16  AND  yT fp16 [b][d][sy], 64x64 tiles via LDS
__global__ void prep_y_kernel(const float* __restrict__ y, _Float16* __restrict__ yf,
                              _Float16* __restrict__ yT)
{
    __shared__ _Float16 LT[64][72];
    const int tid = threadIdx.x;
    const int b   = blockIdx.x >> 7;
    const int rem = blockIdx.x & 127;
    const int sy0 = (rem >> 4) * 64;
    const int d0  = (rem & 15) * 64;
    const int r0 = tid >> 4;
    const int c4 = (tid & 15) * 4;
    #pragma unroll
    for (int i = 0; i < 4; ++i) {
        const int r = r0 + i * 16;
        const float4 v = *(const float4*)&y[((size_t)b * 512 + sy0 + r) * 1024 + d0 + c4];
        const f16x4 hv = {(_Float16)v.x, (_Float16)v.y, (_Float16)v.z, (_Float16)v.w};
        *(f16x4*)&yf[((size_t)b * 512 + sy0 + r) * 1024 + d0 + c4] = hv;
        #pragma unroll
        for (int cc = 0; cc < 4; ++cc) {
            const int c = (cc + (tid & 3)) & 3;
            LT[c4 + c][r] = hv[c];
        }
    }
    __syncthreads();
    #pragma unroll
    for (int i = 0; i < 4; ++i) {
        const int dr = r0 + i * 16;
        const f16x4 v = *(const f16x4*)&LT[dr][(tid & 15) * 4];
        *(f16x4*)&yT[((size_t)b * 1024 + d0 + dr) * 512 + sy0 + (tid & 15) * 4] = v;
    }
}

// W fp32 [k=1024][n=1024] -> WT fp16 [n][k], 64x64 tiles via LDS
__global__ void prep_w_kernel(const float* __restrict__ W, _Float16* __restrict__ WT)
{
    __shared__ _Float16 LT[64][72];
    const int tid = threadIdx.x;
    const int k0 = (blockIdx.x >> 4) * 64;
    const int n0 = (blockIdx.x & 15) * 64;
    const int r0 = tid >> 4;
    const int c4 = (tid & 15) * 4;
    #pragma unroll
    for (int i = 0; i < 4; ++i) {
        const int r = r0 + i * 16;
        const float4 v = *(const float4*)&W[(size_t)(k0 + r) * 1024 + n0 + c4];
        const f16x4 hv = {(_Float16)v.x, (_Float16)v.y, (_Float16)v.z, (_Float16)v.w};
        #pragma unroll
        for (int cc = 0; cc < 4; ++cc) {
            const int c = (cc + (tid & 3)) & 3;
            LT[c4 + c][r] = hv[c];
        }
    }
    __syncthreads();
    #pragma unroll
    for (int i = 0; i < 4; ++i) {
        const int dr = r0 + i * 16;
        const f16x4 v = *(const f16x4*)&LT[dr][(tid & 15) * 4];
        *(f16x4*)&WT[(size_t)(n0 + dr) * 1024 + k0 + (tid & 15) * 4] = v;
    }
}

// fp32 -> fp16 hi + lo residual (x)
__global__ void cvt_hl_kernel(const float4* __restrict__ in, f16x4* __restrict__ oh,
                              f16x4* __restrict__ ol, int n4)
{
    int i = blockIdx.x * blockDim.x + threadIdx.x;
    const int stride = gridDim.x * blockDim.x;
    for (; i < n4; i += stride) {
        const float4 v = in[i];
        const _Float16 h0 = (_Float16)v.x, h1 = (_Float16)v.y,
                       h2 = (_Float16)v.z, h3 = (_Float16)v.w;
        oh[i] = (f16x4){h0, h1, h2, h3};
        ol[i] = (f16x4){(_Float16)(v.x - (float)h0), (_Float16)(v.y - (float)h1),
                        (_Float16)(v.z - (float)h2), (_Float16)(v.w - (float)h3)};
    }
}

// ===================== K1: proj = x@W + b (fp16 2-term) =====================
// 128x128 tile, BK=32, 4 waves, LDS double-buffer, ONE barrier per K-step.
// Row slot (4KB/row): per 8-half group g: h at byte g*32, l at byte g*32+16.
template <bool PRE>
__global__ __launch_bounds__(256, 3)
void proj_f16_kernel(const _Float16* __restrict__ xh, const _Float16* __restrict__ xl,
                     const _Float16* __restrict__ WT, const float* __restrict__ W,
                     const float* __restrict__ bias, char* __restrict__ outc)
{
    __shared__ _Float16 Xh[2][128][32];
    __shared__ _Float16 Xl[2][128][32];
    __shared__ _Float16 Wf[2][128][32];

    const int tid = threadIdx.x, lane = tid & 63, wave = tid >> 6;
    const int swz = (blockIdx.x & 7) * 256 + (blockIdx.x >> 3);
    const int m0 = (swz >> 3) * 128, n0 = (swz & 7) * 128;
    const int wm = (wave >> 1) * 64, wn = (wave & 1) * 64;
    const int ar = lane & 15;
    const int qs  = ((lane >> 4) ^ ((lane >> 1) & 3)) * 8;
    const int gcS = ((lane & 3) ^ ((lane >> 3) & 3)) * 8;
    const int lrow = lane >> 2;
    const int wkb = tid & 7;
    const int wn4 = (tid >> 3) * 4;

    f32x4 acc[4][4];
    #pragma unroll
    for (int i = 0; i < 4; ++i)
        #pragma unroll
        for (int j = 0; j < 4; ++j)
            acc[i][j] = (f32x4){0.f, 0.f, 0.f, 0.f};

    auto STAGE = [&](int t, int bi) {
        const int k0 = t * 32;
        #pragma unroll
        for (int tt = 0; tt < 2; ++tt) {
            const int r = wave * 32 + tt * 16 + lrow;
            async16(&xh[(size_t)(m0 + r) * 1024 + k0 + gcS], &Xh[bi][wave * 32 + tt * 16][0]);
            async16(&xl[(size_t)(m0 + r) * 1024 + k0 + gcS], &Xl[bi][wave * 32 + tt * 16][0]);
            if constexpr (PRE)
                async16(&WT[(size_t)(n0 + r) * 1024 + k0 + gcS], &Wf[bi][wave * 32 + tt * 16][0]);
        }
        if constexpr (!PRE) {
            const size_t wb = (size_t)(k0 + wkb * 4) * 1024 + n0 + wn4;
            const float4 v0 = *(const float4*)&W[wb];
            const float4 v1 = *(const float4*)&W[wb + 1024];
            const float4 v2 = *(const float4*)&W[wb + 2048];
            const float4 v3 = *(const float4*)&W[wb + 3072];
            const float rv[4][4] = {{v0.x, v0.y, v0.z, v0.w},
                                    {v1.x, v1.y, v1.z, v1.w},
                                    {v2.x, v2.y, v2.z, v2.w},
                                    {v3.x, v3.y, v3.z, v3.w}};
            #pragma unroll
            for (int j = 0; j < 4; ++j) {
                const int R = wn4 + j;
                const f16x4 hv = {(_Float16)rv[0][j], (_Float16)rv[1][j],
                                  (_Float16)rv[2][j], (_Float16)rv[3][j]};
                const int c = (wkb >> 1) ^ ((R >> 1) & 3);
                *(f16x4*)&Wf[bi][R][c * 8 + (wkb & 1) * 4] = hv;
            }
        }
    };

    STAGE(0, 0);
    __syncthreads();

    for (int t = 0; t < 32; ++t) {
        const int cur = t & 1;
        if (t < 31) STAGE(t + 1, cur ^ 1);
        f16x8 ah[4], al[4], bf[4];
        #pragma unroll
        for (int f = 0; f < 4; ++f) {
            ah[f] = *(const f16x8*)&Xh[cur][wm + f * 16 + ar][qs];
            al[f] = *(const f16x8*)&Xl[cur][wm + f * 16 + ar][qs];
            bf[f] = *(const f16x8*)&Wf[cur][wn + f * 16 + ar][qs];
        }
        #pragma unroll
        for (int i = 0; i < 4; ++i)
            #pragma unroll
            for (int j = 0; j < 4; ++j) {
                acc[i][j] = MFMA_F16(ah[i], bf[j], acc[i][j]);
                acc[i][j] = MFMA_F16(al[i], bf[j], acc[i][j]);
            }
        __syncthreads();
    }

    // epilogue: +bias, h/l interleaved per 8-half group
    const int q4 = (lane >> 4) * 4;
    #pragma unroll
    for (int j = 0; j < 4; ++j) {
        const int n = n0 + wn + j * 16 + ar;
        const float bv = bias[n];
        const int hidx = (n >> 3) * 16 + (n & 7);
        #pragma unroll
        for (int i = 0; i < 4; ++i)
            #pragma unroll
            for (int r = 0; r < 4; ++r) {
                const int R = m0 + wm + i * 16 + q4 + r;
                const float v = acc[i][j][r] + bv;
                const _Float16 h = (_Float16)v;
                const _Float16 l = (_Float16)(v - (float)h);
                _Float16* rowp = (_Float16*)(outc + (size_t)R * 4096);
                rowp[hidx] = h;
                rowp[hidx + 8] = l;
            }
    }
}

// ================= K2: attention per (batch, 64 sx rows), fp16 ==============
// Phase 0: col-split waves, full unroll, counted vmcnt(8), A depth-2 prefetch.
// Phase 2: col-split, Yt dbuf, counted vmcnt. LDS 81920B (2 blocks/CU).
__global__ __launch_bounds__(256, 2)
void attn_f16_kernel(const _Float16* __restrict__ yf, const _Float16* __restrict__ yT,
                     char* __restrict__ outc)
{
    __shared__ __align__(16) char smem[81920];
    _Float16 (*Yst)[32] = (_Float16(*)[32])smem;            // [512][32] phase 0
    _Float16* Pb        = (_Float16*)smem;                  // [64][512] swz, phase 1/2
    _Float16 (*Yt0)[32] = (_Float16(*)[32])(smem + 65536);  // [128][32] phase 2 buf0
    _Float16 (*Yt1)[32] = (_Float16(*)[32])(smem + 73728);  // [128][32] phase 2 buf1
    float*    Red       = (float*)(smem + 73728);           // [512] phase 1 (alias Yt1)

    const int tid = threadIdx.x, lane = tid & 63, wave = tid >> 6;
    const int swzb = (blockIdx.x & 7) * 64 + (blockIdx.x >> 3);
    const int b = swzb >> 3, sx0 = (swzb & 7) * 64;
    const int pbase = b * 512 + sx0;
    const int ar = lane & 15, q = lane >> 4;
    const int qs  = (q ^ ((lane >> 1) & 3)) * 8;
    const int gcS = ((lane & 3) ^ ((lane >> 3) & 3)) * 8;
    const int lrow = lane >> 2;
    const size_t ybase = (size_t)b * 512 * 1024;

    // ---- phase 0: S = proj @ y^T, wave w -> cols [128w, 128w+128) ----
    f32x4 s2[4][8];
    #pragma unroll
    for (int ri = 0; ri < 4; ++ri)
        #pragma unroll
        for (int t = 0; t < 8; ++t)
            s2[ri][t] = (f32x4){0.f, 0.f, 0.f, 0.f};

    const char* aptr = outc + (size_t)(pbase + ar) * 4096;  // + ri*65536

    f16x8 AH[34][4], AL[34][4];   // SSA under full unroll (compile-time idx)

    // prologue: S(0), A(0), A(1)   [24 vmem in flight]
    #pragma unroll
    for (int t = 0; t < 8; ++t) {
        const int r = wave * 128 + t * 16 + lrow;
        async16(&yf[ybase + (size_t)r * 1024 + gcS], &Yst[wave * 128 + t * 16][0]);
    }
    #pragma unroll
    for (int kk = 0; kk < 2; ++kk)
        #pragma unroll
        for (int ri = 0; ri < 4; ++ri) {
            AH[kk][ri] = *(const f16x8*)(aptr + (size_t)ri * 65536 + (kk * 4 + q) * 32);
            AL[kk][ri] = *(const f16x8*)(aptr + (size_t)ri * 65536 + (kk * 4 + q) * 32 + 16);
        }

    #pragma unroll
    for (int kk = 0; kk < 32; ++kk) {
        if (kk < 31) { WAIT_VM(8); } else { WAIT_VM(0); }
        // half A: frags t=0..3, restage rows 0..63 of stripe, A(kk+2)
        f16x8 bfA[4];
        #pragma unroll
        for (int t = 0; t < 4; ++t)
            bfA[t] = *(const f16x8*)&Yst[wave * 128 + t * 16 + ar][qs];
        WAIT_LGKM0();
        if (kk < 31) {
            const int k1 = (kk + 1) * 32;
            #pragma unroll
            for (int t = 0; t < 4; ++t) {
                const int r = wave * 128 + t * 16 + lrow;
                async16(&yf[ybase + (size_t)r * 1024 + k1 + gcS], &Yst[wave * 128 + t * 16][0]);
            }
        }
        if (kk < 30) {
            #pragma unroll
            for (int ri = 0; ri < 4; ++ri) {
                AH[kk + 2][ri] = *(const f16x8*)(aptr + (size_t)ri * 65536 + ((kk + 2) * 4 + q) * 32);
                AL[kk + 2][ri] = *(const f16x8*)(aptr + (size_t)ri * 65536 + ((kk + 2) * 4 + q) * 32 + 16);
            }
        }
        SB0();
        #pragma unroll
        for (int ri = 0; ri < 4; ++ri)
            #pragma unroll
            for (int t = 0; t < 4; ++t) {
                s2[ri][t] = MFMA_F16(AH[kk][ri], bfA[t], s2[ri][t]);
                s2[ri][t] = MFMA_F16(AL[kk][ri], bfA[t], s2[ri][t]);
            }
        // half B: frags t=4..7, restage rows 64..127
        f16x8 bfB[4];
        #pragma unroll
        for (int t = 4; t < 8; ++t)
            bfB[t - 4] = *(const f16x8*)&Yst[wave * 128 + t * 16 + ar][qs];
        WAIT_LGKM0();
        if (kk < 31) {
            const int k1 = (kk + 1) * 32;
            #pragma unroll
            for (int t = 4; t < 8; ++t) {
                const int r = wave * 128 + t * 16 + lrow;
                async16(&yf[ybase + (size_t)r * 1024 + k1 + gcS], &Yst[wave * 128 + t * 16][0]);
            }
        }
        SB0();
        #pragma unroll
        for (int ri = 0; ri < 4; ++ri)
            #pragma unroll
            for (int t = 4; t < 8; ++t) {
                s2[ri][t] = MFMA_F16(AH[kk][ri], bfB[t - 4], s2[ri][t]);
                s2[ri][t] = MFMA_F16(AL[kk][ri], bfB[t - 4], s2[ri][t]);
            }
    }

    // ---- phase 1: softmax, cross-wave combine via Red ----
    float pm[4][4];
    #pragma unroll
    for (int ri = 0; ri < 4; ++ri)
        #pragma unroll
        for (int r = 0; r < 4; ++r) {
            float m = -3.0e38f;
            #pragma unroll
            for (int t = 0; t < 8; ++t) m = fmaxf(m, s2[ri][t][r]);
            pm[ri][r] = m;
        }
    #pragma unroll
    for (int off = 1; off < 16; off <<= 1)
        #pragma unroll
        for (int ri = 0; ri < 4; ++ri)
            #pragma unroll
            for (int r = 0; r < 4; ++r)
                pm[ri][r] = fmaxf(pm[ri][r], __shfl_xor(pm[ri][r], off, 64));
    if (ar == 0) {
        #pragma unroll
        for (int ri = 0; ri < 4; ++ri)
            #pragma unroll
            for (int r = 0; r < 4; ++r)
                Red[wave * 64 + ri * 16 + q * 4 + r] = pm[ri][r];
    }
    __syncthreads();
    float gm[4][4];
    #pragma unroll
    for (int ri = 0; ri < 4; ++ri)
        #pragma unroll
        for (int r = 0; r < 4; ++r) {
            const int row = ri * 16 + q * 4 + r;
            gm[ri][r] = fmaxf(fmaxf(Red[row], Red[64 + row]),
                              fmaxf(Red[128 + row], Red[192 + row]));
        }
    float ps[4][4];
    #pragma unroll
    for (int ri = 0; ri < 4; ++ri)
        #pragma unroll
        for (int r = 0; r < 4; ++r) {
            float sum = 0.f;
            #pragma unroll
            for (int t = 0; t < 8; ++t) {
                const float e = __expf(s2[ri][t][r] - gm[ri][r]);
                s2[ri][t][r] = e;
                sum += e;
            }
            ps[ri][r] = sum;
        }
    #pragma unroll
    for (int off = 1; off < 16; off <<= 1)
        #pragma unroll
        for (int ri = 0; ri < 4; ++ri)
            #pragma unroll
            for (int r = 0; r < 4; ++r)
                ps[ri][r] += __shfl_xor(ps[ri][r], off, 64);
    if (ar == 0) {
        #pragma unroll
        for (int ri = 0; ri < 4; ++ri)
            #pragma unroll
            for (int r = 0; r < 4; ++r)
                Red[256 + wave * 64 + ri * 16 + q * 4 + r] = ps[ri][r];
    }
    __syncthreads();
    float inv[4][4];
    #pragma unroll
    for (int ri = 0; ri < 4; ++ri)
        #pragma unroll
        for (int r = 0; r < 4; ++r) {
            const int row = 256 + ri * 16 + q * 4 + r;
            inv[ri][r] = 1.0f / (Red[row] + Red[64 + row] + Red[128 + row] + Red[192 + row]);
        }
    // write P, chunk-XOR swizzle: chunk c -> c ^ (row&7)
    #pragma unroll
    for (int ri = 0; ri < 4; ++ri)
        #pragma unroll
        for (int t = 0; t < 8; ++t)
            #pragma unroll
            for (int r = 0; r < 4; ++r) {
                const int row = ri * 16 + q * 4 + r;
                const int c = wave * 16 + t * 2 + (ar >> 3);
                Pb[row * 512 + ((c ^ (row & 7)) << 3) + (ar & 7)]
                    = (_Float16)(s2[ri][t][r] * inv[ri][r]);
            }
    __syncthreads();   // Pbuf complete; Red dead -> Yt1 reusable

    // ---- phase 2: O = P @ y via yT; wave w -> d cols [dc*128+32w, +32) ----
    float* outF = (float*)outc;
    // prologue: stage it=0 -> Yt0, it=1 -> Yt1
    #pragma unroll
    for (int t = 0; t < 2; ++t) {
        const int r = wave * 32 + t * 16 + lrow;
        async16(&yT[(size_t)(b * 1024 + 0 * 128 + r) * 512 + 0 * 32 + gcS],
                &Yt0[wave * 32 + t * 16][0]);
    }
    #pragma unroll
    for (int t = 0; t < 2; ++t) {
        const int r = wave * 32 + t * 16 + lrow;
        async16(&yT[(size_t)(b * 1024 + 0 * 128 + r) * 512 + 1 * 32 + gcS],
                &Yt1[wave * 32 + t * 16][0]);
    }

    for (int dc = 0; dc < 8; ++dc) {
        f32x4 o2[4][2];
        #pragma unroll
        for (int ri = 0; ri < 4; ++ri)
            #pragma unroll
            for (int t = 0; t < 2; ++t)
                o2[ri][t] = (f32x4){0.f, 0.f, 0.f, 0.f};

        #pragma unroll
        for (int kk = 0; kk < 16; ++kk) {
            if (kk == 0) {
                if (dc == 0) { WAIT_VM(2); } else { WAIT_VM(10); }
            } else if (kk == 15) {
                if (dc == 7) { WAIT_VM(0); } else { WAIT_VM(2); }
            } else {
                WAIT_VM(2);
            }
            _Float16 (*Ycur)[32] = (kk & 1) ? Yt1 : Yt0;
            f16x8 a2[4], b2[2];
            #pragma unroll
            for (int ri = 0; ri < 4; ++ri) {
                const int rowa = ri * 16 + ar;
                a2[ri] = *(const f16x8*)&Pb[rowa * 512 + (((kk * 4 + q) ^ (ar & 7)) << 3)];
            }
            #pragma unroll
            for (int t = 0; t < 2; ++t)
                b2[t] = *(const f16x8*)&Ycur[wave * 32 + t * 16 + ar][qs];
            WAIT_LGKM0();
            {   // stage it+2 (same parity buffer), if within range
                const int kk2 = (kk + 2) & 15;
                const int dc2 = dc + ((kk + 2) >> 4);
                if (dc2 < 8) {
                    #pragma unroll
                    for (int t = 0; t < 2; ++t) {
                        const int r = wave * 32 + t * 16 + lrow;
                        async16(&yT[(size_t)(b * 1024 + dc2 * 128 + r) * 512 + kk2 * 32 + gcS],
                                &Ycur[wave * 32 + t * 16][0]);
                    }
                }
            }
            SB0();
            #pragma unroll
            for (int ri = 0; ri < 4; ++ri)
                #pragma unroll
                for (int t = 0; t < 2; ++t)
                    o2[ri][t] = MFMA_F16(a2[ri], b2[t], o2[ri][t]);
        }
        #pragma unroll
        for (int ri = 0; ri < 4; ++ri)
            #pragma unroll
            for (int t = 0; t < 2; ++t)
                #pragma unroll
                for (int r = 0; r < 4; ++r)
                    outF[(size_t)(pbase + ri * 16 + q * 4 + r) * 1024
                         + dc * 128 + wave * 32 + t * 16 + ar] = o2[ri][t][r];
    }
}

// ===================== fallback path (round-1, known good) ==================

__device__ __forceinline__ void cvt4(const float4 v, bf16x4& h, bf16x4& l) {
    const float f0 = v.x, f1 = v.y, f2 = v.z, f3 = v.w;
    const __bf16 h0 = (__bf16)f0, h1 = (__bf16)f1, h2 = (__bf16)f2, h3 = (__bf16)f3;
    h = (bf16x4){h0, h1, h2, h3};
    l = (bf16x4){(__bf16)(f0 - (float)h0), (__bf16)(f1 - (float)h1),
                 (__bf16)(f2 - (float)h2), (__bf16)(f3 - (float)h3)};
}

__global__ __launch_bounds__(256, 2)
void proj_kernel_fb(const float* __restrict__ x, const float* __restrict__ W,
                    const float* __restrict__ bias, float* __restrict__ proj)
{
    __shared__ __bf16 Ah[128][40];
    __shared__ __bf16 Al[128][40];
    __shared__ __bf16 Bh[128][40];
    __shared__ __bf16 Bl[128][40];

    const int tid = threadIdx.x, lane = tid & 63, wave = tid >> 6;
    const int wm = (wave >> 1) * 64, wn = (wave & 1) * 64;
    const int m0 = (blockIdx.x >> 3) * 128, n0 = (blockIdx.x & 7) * 128;
    const int ar = lane & 15, ak = (lane >> 4) * 8;

    f32x4 acc[4][4];
    #pragma unroll
    for (int i = 0; i < 4; ++i)
        #pragma unroll
        for (int j = 0; j < 4; ++j)
            acc[i][j] = (f32x4){0.f, 0.f, 0.f, 0.f};

    const int xr = tid >> 3, xc = (tid & 7) * 4;
    const int wkb = tid >> 5, wn4 = (tid & 31) * 4;

    for (int k0 = 0; k0 < 1024; k0 += 32) {
        __syncthreads();
        #pragma unroll
        for (int it = 0; it < 4; ++it) {
            const int r = xr + it * 32;
            const float4 v = *(const float4*)&x[(size_t)(m0 + r) * 1024 + k0 + xc];
            bf16x4 h, l; cvt4(v, h, l);
            *(bf16x4*)&Ah[r][xc] = h;
            *(bf16x4*)&Al[r][xc] = l;
        }
        {
            const size_t wb = (size_t)(k0 + wkb * 4) * 1024 + n0 + wn4;
            const float4 v0 = *(const float4*)&W[wb];
            const float4 v1 = *(const float4*)&W[wb + 1024];
            const float4 v2 = *(const float4*)&W[wb + 2048];
            const float4 v3 = *(const float4*)&W[wb + 3072];
            const float rv[4][4] = {{v0.x, v0.y, v0.z, v0.w},
                                    {v1.x, v1.y, v1.z, v1.w},
                                    {v2.x, v2.y, v2.z, v2.w},
                                    {v3.x, v3.y, v3.z, v3.w}};
            #pragma unroll
            for (int j = 0; j < 4; ++j) {
                bf16x4 h, l;
                #pragma unroll
                for (int kk = 0; kk < 4; ++kk) {
                    const float f = rv[kk][j];
                    const __bf16 hb = (__bf16)f;
                    h[kk] = hb;
                    l[kk] = (__bf16)(f - (float)hb);
                }
                *(bf16x4*)&Bh[wn4 + j][wkb * 4] = h;
                *(bf16x4*)&Bl[wn4 + j][wkb * 4] = l;
            }
        }
        __syncthreads();

        bf16x8 a_h[4], a_l[4], b_h[4], b_l[4];
        #pragma unroll
        for (int f = 0; f < 4; ++f) {
            a_h[f] = *(const bf16x8*)&Ah[wm + f * 16 + ar][ak];
            a_l[f] = *(const bf16x8*)&Al[wm + f * 16 + ar][ak];
            b_h[f] = *(const bf16x8*)&Bh[wn + f * 16 + ar][ak];
            b_l[f] = *(const bf16x8*)&Bl[wn + f * 16 + ar][ak];
        }
        #pragma unroll
        for (int i = 0; i < 4; ++i)
            #pragma unroll
            for (int j = 0; j < 4; ++j) {
                acc[i][j] = MFMA_BF16(a_h[i], b_h[j], acc[i][j]);
                acc[i][j] = MFMA_BF16(a_l[i], b_h[j], acc[i][j]);
                acc[i][j] = MFMA_BF16(a_h[i], b_l[j], acc[i][j]);
            }
    }

    const int q4 = (lane >> 4) * 4;
    #pragma unroll
    for (int j = 0; j < 4; ++j) {
        const int n = n0 + wn + j * 16 + ar;
        const float bv = bias[n];
        #pragma unroll
        for (int i = 0; i < 4; ++i) {
            const size_t base = (size_t)(m0 + wm + i * 16 + q4) * 1024 + n;
            #pragma unroll
            for (int r = 0; r < 4; ++r)
                proj[base + (size_t)r * 1024] = acc[i][j][r] + bv;
        }
    }
}

__global__ __launch_bounds__(256, 1)
void attn_kernel_fb(const float* __restrict__ y, float* __restrict__ out)
{
    __shared__ __bf16 Ph[64][40];
    __shared__ __bf16 Pl[64][40];
    __shared__ __bf16 Yh[128][40];
    __shared__ __bf16 Yl[128][40];
    __shared__ __bf16 Pbuf[64][520];

    const int tid = threadIdx.x, lane = tid & 63, wave = tid >> 6;
    const int b = blockIdx.x >> 3, sx0 = (blockIdx.x & 7) * 64;
    const size_t ybase = (size_t)b * 512 * 1024;
    const size_t pbase = ((size_t)b * 512 + sx0) * 1024;
    const int ar = lane & 15, ak = (lane >> 4) * 8, q = lane >> 4;

    f32x4 s[4][8];
    #pragma unroll
    for (int nb = 0; nb < 4; ++nb)
        #pragma unroll
        for (int f = 0; f < 8; ++f)
            s[nb][f] = (f32x4){0.f, 0.f, 0.f, 0.f};

    const int pr = tid >> 3, pc = (tid & 7) * 4;

    for (int k0 = 0; k0 < 1024; k0 += 32) {
        __syncthreads();
        #pragma unroll
        for (int it = 0; it < 2; ++it) {
            const int r = pr + it * 32;
            const float4 v = *(const float4*)&out[pbase + (size_t)r * 1024 + k0 + pc];
            bf16x4 h, l; cvt4(v, h, l);
            *(bf16x4*)&Ph[r][pc] = h;
            *(bf16x4*)&Pl[r][pc] = l;
        }
        #pragma unroll
        for (int nb = 0; nb < 4; ++nb) {
            if (nb) __syncthreads();
            const int sy0 = nb * 128;
            #pragma unroll
            for (int it = 0; it < 4; ++it) {
                const int r = pr + it * 32;
                const float4 v = *(const float4*)&y[ybase + (size_t)(sy0 + r) * 1024 + k0 + pc];
                bf16x4 h, l; cvt4(v, h, l);
                *(bf16x4*)&Yh[r][pc] = h;
                *(bf16x4*)&Yl[r][pc] = l;
            }
            __syncthreads();
            const bf16x8 a_h = *(const bf16x8*)&Ph[wave * 16 + ar][ak];
            const bf16x8 a_l = *(const bf16x8*)&Pl[wave * 16 + ar][ak];
            #pragma unroll
            for (int f = 0; f < 8; ++f) {
                const bf16x8 b_h = *(const bf16x8*)&Yh[f * 16 + ar][ak];
                const bf16x8 b_l = *(const bf16x8*)&Yl[f * 16 + ar][ak];
                s[nb][f] = MFMA_BF16(a_h, b_h, s[nb][f]);
                s[nb][f] = MFMA_BF16(a_l, b_h, s[nb][f]);
                s[nb][f] = MFMA_BF16(a_h, b_l, s[nb][f]);
            }
        }
    }

    #pragma unroll
    for (int r = 0; r < 4; ++r) {
        float m = -3.0e38f;
        #pragma unroll
        for (int nb = 0; nb < 4; ++nb)
            #pragma unroll
            for (int f = 0; f < 8; ++f)
                m = fmaxf(m, s[nb][f][r]);
        #pragma unroll
        for (int off = 1; off < 16; off <<= 1)
            m = fmaxf(m, __shfl_xor(m, off, 64));
        float sum = 0.f;
        #pragma unroll
        for (int nb = 0; nb < 4; ++nb)
            #pragma unroll
            for (int f = 0; f < 8; ++f) {
                const float e = __expf(s[nb][f][r] - m);
                s[nb][f][r] = e;
                sum += e;
            }
        #pragma unroll
        for (int off = 1; off < 16; off <<= 1)
            sum += __shfl_xor(sum, off, 64);
        const float inv = 1.0f / sum;
        #pragma unroll
        for (int nb = 0; nb < 4; ++nb)
            #pragma unroll
            for (int f = 0; f < 8; ++f)
                s[nb][f][r] *= inv;
    }
    #pragma unroll
    for (int nb = 0; nb < 4; ++nb)
        #pragma unroll
        for (int f = 0; f < 8; ++f)
            #pragma unroll
            for (int r = 0; r < 4; ++r)
                Pbuf[wave * 16 + q * 4 + r][nb * 128 + f * 16 + ar] = (__bf16)s[nb][f][r];

    const int y2kb = tid >> 5, y2n4 = (tid & 31) * 4;
    for (int d0 = 0; d0 < 1024; d0 += 128) {
        f32x4 o[8];
        #pragma unroll
        for (int f = 0; f < 8; ++f) o[f] = (f32x4){0.f, 0.f, 0.f, 0.f};

        for (int k0 = 0; k0 < 512; k0 += 32) {
            __syncthreads();
            const size_t yb = ybase + (size_t)(k0 + y2kb * 4) * 1024 + d0 + y2n4;
            const float4 v0 = *(const float4*)&y[yb];
            const float4 v1 = *(const float4*)&y[yb + 1024];
            const float4 v2 = *(const float4*)&y[yb + 2048];
            const float4 v3 = *(const float4*)&y[yb + 3072];
            const float rv[4][4] = {{v0.x, v0.y, v0.z, v0.w},
                                    {v1.x, v1.y, v1.z, v1.w},
                                    {v2.x, v2.y, v2.z, v2.w},
                                    {v3.x, v3.y, v3.z, v3.w}};
            #pragma unroll
            for (int j = 0; j < 4; ++j) {
                const bf16x4 h = (bf16x4){(__bf16)rv[0][j], (__bf16)rv[1][j],
                                          (__bf16)rv[2][j], (__bf16)rv[3][j]};
                *(bf16x4*)&Yh[y2n4 + j][y2kb * 4] = h;
            }
            __syncthreads();
            const bf16x8 a = *(const bf16x8*)&Pbuf[wave * 16 + ar][k0 + ak];
            #pragma unroll
            for (int f = 0; f < 8; ++f) {
                const bf16x8 bb = *(const bf16x8*)&Yh[f * 16 + ar][ak];
                o[f] = MFMA_BF16(a, bb, o[f]);
            }
        }
        #pragma unroll
        for (int f = 0; f < 8; ++f)
            #pragma unroll
            for (int r = 0; r < 4; ++r)
                out[pbase + (size_t)(wave * 16 + q * 4 + r) * 1024 + d0 + f * 16 + ar] = o[f][r];
    }
}

// ============================== launch ======================================

extern "C" void kernel_launch(void* const* d_in, const int* in_sizes, int n_in,
                              void* d_out, int out_size, void* d_ws, size_t ws_size,
                              hipStream_t stream) {
    (void)in_sizes; (void)n_in; (void)out_size;
    const float* x    = (const float*)d_in[0];
    const float* y    = (const float*)d_in[1];
    const float* W    = (const float*)d_in[2];
    const float* bias = (const float*)d_in[3];

    if (ws_size >= 268435456ULL) {
        _Float16* yf = (_Float16*)d_ws;
        _Float16* yT = yf + 33554432;
        _Float16* xh = yT + 33554432;
        _Float16* xl = xh + 33554432;
        _Float16* WT = xl + 33554432;
        const bool pre = ws_size >= 268435456ULL + 2097152ULL;

        prep_y_kernel<<<dim3(8192), dim3(256), 0, stream>>>(y, yf, yT);
        cvt_hl_kernel<<<dim3(2048), dim3(256), 0, stream>>>((const float4*)x, (f16x4*)xh,
                                                            (f16x4*)xl, 8388608);
        if (pre) {
            prep_w_kernel<<<dim3(256), dim3(256), 0, stream>>>(W, WT);
            proj_f16_kernel<true><<<dim3(2048), dim3(256), 0, stream>>>(xh, xl, WT, W, bias,
                                                                        (char*)d_out);
        } else {
            proj_f16_kernel<false><<<dim3(2048), dim3(256), 0, stream>>>(xh, xl, nullptr, W,
                                                                         bias, (char*)d_out);
        }
        attn_f16_kernel<<<dim3(512), dim3(256), 0, stream>>>(yf, yT, (char*)d_out);
    } else {
        float* out = (float*)d_out;
        proj_kernel_fb<<<dim3(256 * 8), dim3(256), 0, stream>>>(x, W, bias, out);
        attn_kernel_fb<<<dim3(64 * 8), dim3(256), 0, stream>>>(y, out);
    }
}

// Round 4
// 707.188 us; speedup vs baseline: 1.1490x; 1.1490x over previous
//
#include <hip/hip_runtime.h>

// ESIM layer: out = softmax((x@W + b) @ y^T) @ y
// B=64, Sx=Sy=512, D=1024, fp32 in/out.
//
// Round-5 (fix of round-4 scratch disaster; attn rebuilt around direct
// global->reg fragment loads):
//  * attn col-split means each wave is sole consumer of its stripe -> LDS
//    staging had zero reuse. Removed. B-frags read straight from L2-resident
//    yf/yT; proj A-frags (HBM) use a depth-2 rotation in NAMED registers
//    (A0/A1, 64 VGPR) refilled after use -> 1 full iter (~600cyc) of cover.
//  * No barriers / manual waitcnt in attn k-loops at all (compiler auto-waits
//    on reg loads). LDS = Pbuf[64][520] + Red only (67KB, 2 blocks/CU).
//  * phase 2: wave owns 256 d-cols in 2 epochs of 128 -> Pbuf reads /4,
//    32 MFMA per iter. Accumulators reuse s2's registers (disjoint liveness).
//  * proj unchanged from round-4 (dbuf, 1 barrier/K-step, h/l interleaved
//    32B groups in row slots -- phase-0 A-loads rely on that layout).

typedef float  f32x4  __attribute__((ext_vector_type(4)));
typedef _Float16 f16x8 __attribute__((ext_vector_type(8)));
typedef _Float16 f16x4 __attribute__((ext_vector_type(4)));
typedef __bf16 bf16x8 __attribute__((ext_vector_type(8)));
typedef __bf16 bf16x4 __attribute__((ext_vector_type(4)));

#define MFMA_F16(a, b, c)  __builtin_amdgcn_mfma_f32_16x16x32_f16((a), (b), (c), 0, 0, 0)
#define MFMA_BF16(a, b, c) __builtin_amdgcn_mfma_f32_16x16x32_bf16((a), (b), (c), 0, 0, 0)

__device__ __forceinline__ void async16(const void* g, void* lds) {
    __builtin_amdgcn_global_load_lds(
        (const __attribute__((address_space(1))) unsigned int*)g,
        (__attribute__((address_space(3))) unsigned int*)lds, 16, 0, 0);
}

// ========================= prep kernels =====================================

// fused: y fp32 -> yf fp16  AND  yT fp16 [b][d][sy], 64x64 tiles via LDS
__global__ void prep_y_kernel(const float* __restrict__ y, _Float16* __restrict__ yf,
                              _Float16* __restrict__ yT)
{
    __shared__ _Float16 LT[64][72];
    const int tid = threadIdx.x;
    const int b   = blockIdx.x >> 7;
    const int rem = blockIdx.x & 127;
    const int sy0 = (rem >> 4) * 64;
    const int d0  = (rem & 15) * 64;
    const int r0 = tid >> 4;
    const int c4 = (tid & 15) * 4;
    #pragma unroll
    for (int i = 0; i < 4; ++i) {
        const int r = r0 + i * 16;
        const float4 v = *(const float4*)&y[((size_t)b * 512 + sy0 + r) * 1024 + d0 + c4];
        const f16x4 hv = {(_Float16)v.x, (_Float16)v.y, (_Float16)v.z, (_Float16)v.w};
        *(f16x4*)&yf[((size_t)b * 512 + sy0 + r) * 1024 + d0 + c4] = hv;
        #pragma unroll
        for (int cc = 0; cc < 4; ++cc) {
            const int c = (cc + (tid & 3)) & 3;
            LT[c4 + c][r] = hv[c];
        }
    }
    __syncthreads();
    #pragma unroll
    for (int i = 0; i < 4; ++i) {
        const int dr = r0 + i * 16;
        const f16x4 v = *(const f16x4*)&LT[dr][(tid & 15) * 4];
        *(f16x4*)&yT[((size_t)b * 1024 + d0 + dr) * 512 + sy0 + (tid & 15) * 4] = v;
    }
}

// W fp32 [k=1024][n=1024] -> WT fp16 [n][k], 64x64 tiles via LDS
__global__ void prep_w_kernel(const float* __restrict__ W, _Float16* __restrict__ WT)
{
    __shared__ _Float16 LT[64][72];
    const int tid = threadIdx.x;
    const int k0 = (blockIdx.x >> 4) * 64;
    const int n0 = (blockIdx.x & 15) * 64;
    const int r0 = tid >> 4;
    const int c4 = (tid & 15) * 4;
    #pragma unroll
    for (int i = 0; i < 4; ++i) {
        const int r = r0 + i * 16;
        const float4 v = *(const float4*)&W[(size_t)(k0 + r) * 1024 + n0 + c4];
        const f16x4 hv = {(_Float16)v.x, (_Float16)v.y, (_Float16)v.z, (_Float16)v.w};
        #pragma unroll
        for (int cc = 0; cc < 4; ++cc) {
            const int c = (cc + (tid & 3)) & 3;
            LT[c4 + c][r] = hv[c];
        }
    }
    __syncthreads();
    #pragma unroll
    for (int i = 0; i < 4; ++i) {
        const int dr = r0 + i * 16;
        const f16x4 v = *(const f16x4*)&LT[dr][(tid & 15) * 4];
        *(f16x4*)&WT[(size_t)(n0 + dr) * 1024 + k0 + (tid & 15) * 4] = v;
    }
}

// fp32 -> fp16 hi + lo residual (x)
__global__ void cvt_hl_kernel(const float4* __restrict__ in, f16x4* __restrict__ oh,
                              f16x4* __restrict__ ol, int n4)
{
    int i = blockIdx.x * blockDim.x + threadIdx.x;
    const int stride = gridDim.x * blockDim.x;
    for (; i < n4; i += stride) {
        const float4 v = in[i];
        const _Float16 h0 = (_Float16)v.x, h1 = (_Float16)v.y,
                       h2 = (_Float16)v.z, h3 = (_Float16)v.w;
        oh[i] = (f16x4){h0, h1, h2, h3};
        ol[i] = (f16x4){(_Float16)(v.x - (float)h0), (_Float16)(v.y - (float)h1),
                        (_Float16)(v.z - (float)h2), (_Float16)(v.w - (float)h3)};
    }
}

// ===================== K1: proj = x@W + b (fp16 2-term) =====================
// 128x128 tile, BK=32, 4 waves, LDS double-buffer, ONE barrier per K-step.
// Row slot (4KB/row): per 8-half group g: h at byte g*32, l at byte g*32+16.
template <bool PRE>
__global__ __launch_bounds__(256, 3)
void proj_f16_kernel(const _Float16* __restrict__ xh, const _Float16* __restrict__ xl,
                     const _Float16* __restrict__ WT, const float* __restrict__ W,
                     const float* __restrict__ bias, char* __restrict__ outc)
{
    __shared__ _Float16 Xh[2][128][32];
    __shared__ _Float16 Xl[2][128][32];
    __shared__ _Float16 Wf[2][128][32];

    const int tid = threadIdx.x, lane = tid & 63, wave = tid >> 6;
    const int swz = (blockIdx.x & 7) * 256 + (blockIdx.x >> 3);
    const int m0 = (swz >> 3) * 128, n0 = (swz & 7) * 128;
    const int wm = (wave >> 1) * 64, wn = (wave & 1) * 64;
    const int ar = lane & 15;
    const int qs  = ((lane >> 4) ^ ((lane >> 1) & 3)) * 8;
    const int gcS = ((lane & 3) ^ ((lane >> 3) & 3)) * 8;
    const int lrow = lane >> 2;
    const int wkb = tid & 7;
    const int wn4 = (tid >> 3) * 4;

    f32x4 acc[4][4];
    #pragma unroll
    for (int i = 0; i < 4; ++i)
        #pragma unroll
        for (int j = 0; j < 4; ++j)
            acc[i][j] = (f32x4){0.f, 0.f, 0.f, 0.f};

    auto STAGE = [&](int t, int bi) {
        const int k0 = t * 32;
        #pragma unroll
        for (int tt = 0; tt < 2; ++tt) {
            const int r = wave * 32 + tt * 16 + lrow;
            async16(&xh[(size_t)(m0 + r) * 1024 + k0 + gcS], &Xh[bi][wave * 32 + tt * 16][0]);
            async16(&xl[(size_t)(m0 + r) * 1024 + k0 + gcS], &Xl[bi][wave * 32 + tt * 16][0]);
            if constexpr (PRE)
                async16(&WT[(size_t)(n0 + r) * 1024 + k0 + gcS], &Wf[bi][wave * 32 + tt * 16][0]);
        }
        if constexpr (!PRE) {
            const size_t wb = (size_t)(k0 + wkb * 4) * 1024 + n0 + wn4;
            const float4 v0 = *(const float4*)&W[wb];
            const float4 v1 = *(const float4*)&W[wb + 1024];
            const float4 v2 = *(const float4*)&W[wb + 2048];
            const float4 v3 = *(const float4*)&W[wb + 3072];
            const float rv[4][4] = {{v0.x, v0.y, v0.z, v0.w},
                                    {v1.x, v1.y, v1.z, v1.w},
                                    {v2.x, v2.y, v2.z, v2.w},
                                    {v3.x, v3.y, v3.z, v3.w}};
            #pragma unroll
            for (int j = 0; j < 4; ++j) {
                const int R = wn4 + j;
                const f16x4 hv = {(_Float16)rv[0][j], (_Float16)rv[1][j],
                                  (_Float16)rv[2][j], (_Float16)rv[3][j]};
                const int c = (wkb >> 1) ^ ((R >> 1) & 3);
                *(f16x4*)&Wf[bi][R][c * 8 + (wkb & 1) * 4] = hv;
            }
        }
    };

    STAGE(0, 0);
    __syncthreads();

    for (int t = 0; t < 32; ++t) {
        const int cur = t & 1;
        if (t < 31) STAGE(t + 1, cur ^ 1);
        f16x8 ah[4], al[4], bf[4];
        #pragma unroll
        for (int f = 0; f < 4; ++f) {
            ah[f] = *(const f16x8*)&Xh[cur][wm + f * 16 + ar][qs];
            al[f] = *(const f16x8*)&Xl[cur][wm + f * 16 + ar][qs];
            bf[f] = *(const f16x8*)&Wf[cur][wn + f * 16 + ar][qs];
        }
        #pragma unroll
        for (int i = 0; i < 4; ++i)
            #pragma unroll
            for (int j = 0; j < 4; ++j) {
                acc[i][j] = MFMA_F16(ah[i], bf[j], acc[i][j]);
                acc[i][j] = MFMA_F16(al[i], bf[j], acc[i][j]);
            }
        __syncthreads();
    }

    // epilogue: +bias, h/l interleaved per 8-half group
    const int q4 = (lane >> 4) * 4;
    #pragma unroll
    for (int j = 0; j < 4; ++j) {
        const int n = n0 + wn + j * 16 + ar;
        const float bv = bias[n];
        const int hidx = (n >> 3) * 16 + (n & 7);
        #pragma unroll
        for (int i = 0; i < 4; ++i)
            #pragma unroll
            for (int r = 0; r < 4; ++r) {
                const int R = m0 + wm + i * 16 + q4 + r;
                const float v = acc[i][j][r] + bv;
                const _Float16 h = (_Float16)v;
                const _Float16 l = (_Float16)(v - (float)h);
                _Float16* rowp = (_Float16*)(outc + (size_t)R * 4096);
                rowp[hidx] = h;
                rowp[hidx + 8] = l;
            }
    }
}

// ================= K2: attention per (batch, 64 sx rows), fp16 ==============
// Col-split waves. NO LDS staging: B-frags direct from L2-resident yf/yT;
// A-frags (HBM proj rows) via depth-2 named-register rotation.
__global__ __launch_bounds__(256, 2)
void attn_f16_kernel(const _Float16* __restrict__ yf, const _Float16* __restrict__ yT,
                     char* __restrict__ outc)
{
    __shared__ _Float16 Pbuf[64][520];
    __shared__ float    Red[512];

    const int tid = threadIdx.x, lane = tid & 63, wave = tid >> 6;
    const int swzb = (blockIdx.x & 7) * 64 + (blockIdx.x >> 3);
    const int b = swzb >> 3, sx0 = (swzb & 7) * 64;
    const int pbase = b * 512 + sx0;
    const int ar = lane & 15, q = lane >> 4, qk = q * 8;
    const size_t ybase = (size_t)b * 512 * 1024;

    // ---- phase 0: S = proj @ y^T, wave w -> sy cols [128w, 128w+128) ----
    f32x4 s2[4][8];
    #pragma unroll
    for (int ri = 0; ri < 4; ++ri)
        #pragma unroll
        for (int t = 0; t < 8; ++t)
            s2[ri][t] = (f32x4){0.f, 0.f, 0.f, 0.f};

    const char* aptr = outc + (size_t)(pbase + ar) * 4096;          // + ri*65536
    const _Float16* yw = yf + ybase + (size_t)(wave * 128 + ar) * 1024;  // + t*16384

    f16x8 A0H[4], A0L[4], A1H[4], A1L[4];
    auto LOADA = [&](int kk, f16x8 (&AH)[4], f16x8 (&AL)[4]) {
        #pragma unroll
        for (int ri = 0; ri < 4; ++ri) {
            const char* p = aptr + (size_t)ri * 65536 + (size_t)(kk * 4 + q) * 32;
            AH[ri] = *(const f16x8*)p;
            AL[ri] = *(const f16x8*)(p + 16);
        }
    };

    LOADA(0, A0H, A0L);
    LOADA(1, A1H, A1L);

    for (int kk = 0; kk < 32; kk += 2) {
        {   // even step uses A0; refill A0 <- A(kk+2) after its use
            f16x8 bf[8];
            #pragma unroll
            for (int t = 0; t < 8; ++t)
                bf[t] = *(const f16x8*)&yw[(size_t)t * 16384 + kk * 32 + qk];
            #pragma unroll
            for (int ri = 0; ri < 4; ++ri)
                #pragma unroll
                for (int t = 0; t < 8; ++t) {
                    s2[ri][t] = MFMA_F16(A0H[ri], bf[t], s2[ri][t]);
                    s2[ri][t] = MFMA_F16(A0L[ri], bf[t], s2[ri][t]);
                }
            if (kk + 2 < 32) LOADA(kk + 2, A0H, A0L);
        }
        {   // odd step uses A1; refill A1 <- A(kk+3)
            f16x8 bf[8];
            #pragma unroll
            for (int t = 0; t < 8; ++t)
                bf[t] = *(const f16x8*)&yw[(size_t)t * 16384 + (kk + 1) * 32 + qk];
            #pragma unroll
            for (int ri = 0; ri < 4; ++ri)
                #pragma unroll
                for (int t = 0; t < 8; ++t) {
                    s2[ri][t] = MFMA_F16(A1H[ri], bf[t], s2[ri][t]);
                    s2[ri][t] = MFMA_F16(A1L[ri], bf[t], s2[ri][t]);
                }
            if (kk + 3 < 32) LOADA(kk + 3, A1H, A1L);
        }
    }

    // ---- phase 1: softmax, cross-wave combine via Red ----
    float pm[4][4];
    #pragma unroll
    for (int ri = 0; ri < 4; ++ri)
        #pragma unroll
        for (int r = 0; r < 4; ++r) {
            float m = -3.0e38f;
            #pragma unroll
            for (int t = 0; t < 8; ++t) m = fmaxf(m, s2[ri][t][r]);
            pm[ri][r] = m;
        }
    #pragma unroll
    for (int off = 1; off < 16; off <<= 1)
        #pragma unroll
        for (int ri = 0; ri < 4; ++ri)
            #pragma unroll
            for (int r = 0; r < 4; ++r)
                pm[ri][r] = fmaxf(pm[ri][r], __shfl_xor(pm[ri][r], off, 64));
    if (ar == 0) {
        #pragma unroll
        for (int ri = 0; ri < 4; ++ri)
            #pragma unroll
            for (int r = 0; r < 4; ++r)
                Red[wave * 64 + ri * 16 + q * 4 + r] = pm[ri][r];
    }
    __syncthreads();
    float gm[4][4];
    #pragma unroll
    for (int ri = 0; ri < 4; ++ri)
        #pragma unroll
        for (int r = 0; r < 4; ++r) {
            const int row = ri * 16 + q * 4 + r;
            gm[ri][r] = fmaxf(fmaxf(Red[row], Red[64 + row]),
                              fmaxf(Red[128 + row], Red[192 + row]));
        }
    float ps[4][4];
    #pragma unroll
    for (int ri = 0; ri < 4; ++ri)
        #pragma unroll
        for (int r = 0; r < 4; ++r) {
            float sum = 0.f;
            #pragma unroll
            for (int t = 0; t < 8; ++t) {
                const float e = __expf(s2[ri][t][r] - gm[ri][r]);
                s2[ri][t][r] = e;
                sum += e;
            }
            ps[ri][r] = sum;
        }
    #pragma unroll
    for (int off = 1; off < 16; off <<= 1)
        #pragma unroll
        for (int ri = 0; ri < 4; ++ri)
            #pragma unroll
            for (int r = 0; r < 4; ++r)
                ps[ri][r] += __shfl_xor(ps[ri][r], off, 64);
    if (ar == 0) {
        #pragma unroll
        for (int ri = 0; ri < 4; ++ri)
            #pragma unroll
            for (int r = 0; r < 4; ++r)
                Red[256 + wave * 64 + ri * 16 + q * 4 + r] = ps[ri][r];
    }
    __syncthreads();
    float inv[4][4];
    #pragma unroll
    for (int ri = 0; ri < 4; ++ri)
        #pragma unroll
        for (int r = 0; r < 4; ++r) {
            const int row = 256 + ri * 16 + q * 4 + r;
            inv[ri][r] = 1.0f / (Red[row] + Red[64 + row] + Red[128 + row] + Red[192 + row]);
        }
    #pragma unroll
    for (int ri = 0; ri < 4; ++ri)
        #pragma unroll
        for (int t = 0; t < 8; ++t)
            #pragma unroll
            for (int r = 0; r < 4; ++r)
                Pbuf[ri * 16 + q * 4 + r][wave * 128 + t * 16 + ar]
                    = (_Float16)(s2[ri][t][r] * inv[ri][r]);
    __syncthreads();   // Pbuf complete before phase-2 reads

    // ---- phase 2: O = P @ y via yT; wave w -> d cols [w*256, +256), 2 epochs ----
    float* outF = (float*)outc;
    #pragma unroll
    for (int dc = 0; dc < 2; ++dc) {
        f32x4 o2[4][8];
        #pragma unroll
        for (int ri = 0; ri < 4; ++ri)
            #pragma unroll
            for (int t = 0; t < 8; ++t)
                o2[ri][t] = (f32x4){0.f, 0.f, 0.f, 0.f};

        const _Float16* ytw = yT + ((size_t)b * 1024 + wave * 256 + dc * 128 + ar) * 512;

        for (int kk = 0; kk < 16; ++kk) {
            f16x8 a2[4], b2[8];
            #pragma unroll
            for (int ri = 0; ri < 4; ++ri)
                a2[ri] = *(const f16x8*)&Pbuf[ri * 16 + ar][kk * 32 + qk];
            #pragma unroll
            for (int t = 0; t < 8; ++t)
                b2[t] = *(const f16x8*)&ytw[(size_t)t * 16 * 512 + kk * 32 + qk];
            #pragma unroll
            for (int ri = 0; ri < 4; ++ri)
                #pragma unroll
                for (int t = 0; t < 8; ++t)
                    o2[ri][t] = MFMA_F16(a2[ri], b2[t], o2[ri][t]);
        }
        #pragma unroll
        for (int ri = 0; ri < 4; ++ri)
            #pragma unroll
            for (int t = 0; t < 8; ++t)
                #pragma unroll
                for (int r = 0; r < 4; ++r)
                    outF[(size_t)(pbase + ri * 16 + q * 4 + r) * 1024
                         + wave * 256 + dc * 128 + t * 16 + ar] = o2[ri][t][r];
    }
}

// ===================== fallback path (round-1, known good) ==================

__device__ __forceinline__ void cvt4(const float4 v, bf16x4& h, bf16x4& l) {
    const float f0 = v.x, f1 = v.y, f2 = v.z, f3 = v.w;
    const __bf16 h0 = (__bf16)f0, h1 = (__bf16)f1, h2 = (__bf16)f2, h3 = (__bf16)f3;
    h = (bf16x4){h0, h1, h2, h3};
    l = (bf16x4){(__bf16)(f0 - (float)h0), (__bf16)(f1 - (float)h1),
                 (__bf16)(f2 - (float)h2), (__bf16)(f3 - (float)h3)};
}

__global__ __launch_bounds__(256, 2)
void proj_kernel_fb(const float* __restrict__ x, const float* __restrict__ W,
                    const float* __restrict__ bias, float* __restrict__ proj)
{
    __shared__ __bf16 Ah[128][40];
    __shared__ __bf16 Al[128][40];
    __shared__ __bf16 Bh[128][40];
    __shared__ __bf16 Bl[128][40];

    const int tid = threadIdx.x, lane = tid & 63, wave = tid >> 6;
    const int wm = (wave >> 1) * 64, wn = (wave & 1) * 64;
    const int m0 = (blockIdx.x >> 3) * 128, n0 = (blockIdx.x & 7) * 128;
    const int ar = lane & 15, ak = (lane >> 4) * 8;

    f32x4 acc[4][4];
    #pragma unroll
    for (int i = 0; i < 4; ++i)
        #pragma unroll
        for (int j = 0; j < 4; ++j)
            acc[i][j] = (f32x4){0.f, 0.f, 0.f, 0.f};

    const int xr = tid >> 3, xc = (tid & 7) * 4;
    const int wkb = tid >> 5, wn4 = (tid & 31) * 4;

    for (int k0 = 0; k0 < 1024; k0 += 32) {
        __syncthreads();
        #pragma unroll
        for (int it = 0; it < 4; ++it) {
            const int r = xr + it * 32;
            const float4 v = *(const float4*)&x[(size_t)(m0 + r) * 1024 + k0 + xc];
            bf16x4 h, l; cvt4(v, h, l);
            *(bf16x4*)&Ah[r][xc] = h;
            *(bf16x4*)&Al[r][xc] = l;
        }
        {
            const size_t wb = (size_t)(k0 + wkb * 4) * 1024 + n0 + wn4;
            const float4 v0 = *(const float4*)&W[wb];
            const float4 v1 = *(const float4*)&W[wb + 1024];
            const float4 v2 = *(const float4*)&W[wb + 2048];
            const float4 v3 = *(const float4*)&W[wb + 3072];
            const float rv[4][4] = {{v0.x, v0.y, v0.z, v0.w},
                                    {v1.x, v1.y, v1.z, v1.w},
                                    {v2.x, v2.y, v2.z, v2.w},
                                    {v3.x, v3.y, v3.z, v3.w}};
            #pragma unroll
            for (int j = 0; j < 4; ++j) {
                bf16x4 h, l;
                #pragma unroll
                for (int kk = 0; kk < 4; ++kk) {
                    const float f = rv[kk][j];
                    const __bf16 hb = (__bf16)f;
                    h[kk] = hb;
                    l[kk] = (__bf16)(f - (float)hb);
                }
                *(bf16x4*)&Bh[wn4 + j][wkb * 4] = h;
                *(bf16x4*)&Bl[wn4 + j][wkb * 4] = l;
            }
        }
        __syncthreads();

        bf16x8 a_h[4], a_l[4], b_h[4], b_l[4];
        #pragma unroll
        for (int f = 0; f < 4; ++f) {
            a_h[f] = *(const bf16x8*)&Ah[wm + f * 16 + ar][ak];
            a_l[f] = *(const bf16x8*)&Al[wm + f * 16 + ar][ak];
            b_h[f] = *(const bf16x8*)&Bh[wn + f * 16 + ar][ak];
            b_l[f] = *(const bf16x8*)&Bl[wn + f * 16 + ar][ak];
        }
        #pragma unroll
        for (int i = 0; i < 4; ++i)
            #pragma unroll
            for (int j = 0; j < 4; ++j) {
                acc[i][j] = MFMA_BF16(a_h[i], b_h[j], acc[i][j]);
                acc[i][j] = MFMA_BF16(a_l[i], b_h[j], acc[i][j]);
                acc[i][j] = MFMA_BF16(a_h[i], b_l[j], acc[i][j]);
            }
    }

    const int q4 = (lane >> 4) * 4;
    #pragma unroll
    for (int j = 0; j < 4; ++j) {
        const int n = n0 + wn + j * 16 + ar;
        const float bv = bias[n];
        #pragma unroll
        for (int i = 0; i < 4; ++i) {
            const size_t base = (size_t)(m0 + wm + i * 16 + q4) * 1024 + n;
            #pragma unroll
            for (int r = 0; r < 4; ++r)
                proj[base + (size_t)r * 1024] = acc[i][j][r] + bv;
        }
    }
}

__global__ __launch_bounds__(256, 1)
void attn_kernel_fb(const float* __restrict__ y, float* __restrict__ out)
{
    __shared__ __bf16 Ph[64][40];
    __shared__ __bf16 Pl[64][40];
    __shared__ __bf16 Yh[128][40];
    __shared__ __bf16 Yl[128][40];
    __shared__ __bf16 Pbuf[64][520];

    const int tid = threadIdx.x, lane = tid & 63, wave = tid >> 6;
    const int b = blockIdx.x >> 3, sx0 = (blockIdx.x & 7) * 64;
    const size_t ybase = (size_t)b * 512 * 1024;
    const size_t pbase = ((size_t)b * 512 + sx0) * 1024;
    const int ar = lane & 15, ak = (lane >> 4) * 8, q = lane >> 4;

    f32x4 s[4][8];
    #pragma unroll
    for (int nb = 0; nb < 4; ++nb)
        #pragma unroll
        for (int f = 0; f < 8; ++f)
            s[nb][f] = (f32x4){0.f, 0.f, 0.f, 0.f};

    const int pr = tid >> 3, pc = (tid & 7) * 4;

    for (int k0 = 0; k0 < 1024; k0 += 32) {
        __syncthreads();
        #pragma unroll
        for (int it = 0; it < 2; ++it) {
            const int r = pr + it * 32;
            const float4 v = *(const float4*)&out[pbase + (size_t)r * 1024 + k0 + pc];
            bf16x4 h, l; cvt4(v, h, l);
            *(bf16x4*)&Ph[r][pc] = h;
            *(bf16x4*)&Pl[r][pc] = l;
        }
        #pragma unroll
        for (int nb = 0; nb < 4; ++nb) {
            if (nb) __syncthreads();
            const int sy0 = nb * 128;
            #pragma unroll
            for (int it = 0; it < 4; ++it) {
                const int r = pr + it * 32;
                const float4 v = *(const float4*)&y[ybase + (size_t)(sy0 + r) * 1024 + k0 + pc];
                bf16x4 h, l; cvt4(v, h, l);
                *(bf16x4*)&Yh[r][pc] = h;
                *(bf16x4*)&Yl[r][pc] = l;
            }
            __syncthreads();
            const bf16x8 a_h = *(const bf16x8*)&Ph[wave * 16 + ar][ak];
            const bf16x8 a_l = *(const bf16x8*)&Pl[wave * 16 + ar][ak];
            #pragma unroll
            for (int f = 0; f < 8; ++f) {
                const bf16x8 b_h = *(const bf16x8*)&Yh[f * 16 + ar][ak];
                const bf16x8 b_l = *(const bf16x8*)&Yl[f * 16 + ar][ak];
                s[nb][f] = MFMA_BF16(a_h, b_h, s[nb][f]);
                s[nb][f] = MFMA_BF16(a_l, b_h, s[nb][f]);
                s[nb][f] = MFMA_BF16(a_h, b_l, s[nb][f]);
            }
        }
    }

    #pragma unroll
    for (int r = 0; r < 4; ++r) {
        float m = -3.0e38f;
        #pragma unroll
        for (int nb = 0; nb < 4; ++nb)
            #pragma unroll
            for (int f = 0; f < 8; ++f)
                m = fmaxf(m, s[nb][f][r]);
        #pragma unroll
        for (int off = 1; off < 16; off <<= 1)
            m = fmaxf(m, __shfl_xor(m, off, 64));
        float sum = 0.f;
        #pragma unroll
        for (int nb = 0; nb < 4; ++nb)
            #pragma unroll
            for (int f = 0; f < 8; ++f) {
                const float e = __expf(s[nb][f][r] - m);
                s[nb][f][r] = e;
                sum += e;
            }
        #pragma unroll
        for (int off = 1; off < 16; off <<= 1)
            sum += __shfl_xor(sum, off, 64);
        const float inv = 1.0f / sum;
        #pragma unroll
        for (int nb = 0; nb < 4; ++nb)
            #pragma unroll
            for (int f = 0; f < 8; ++f)
                s[nb][f][r] *= inv;
    }
    #pragma unroll
    for (int nb = 0; nb < 4; ++nb)
        #pragma unroll
        for (int f = 0; f < 8; ++f)
            #pragma unroll
            for (int r = 0; r < 4; ++r)
                Pbuf[wave * 16 + q * 4 + r][nb * 128 + f * 16 + ar] = (__bf16)s[nb][f][r];

    const int y2kb = tid >> 5, y2n4 = (tid & 31) * 4;
    for (int d0 = 0; d0 < 1024; d0 += 128) {
        f32x4 o[8];
        #pragma unroll
        for (int f = 0; f < 8; ++f) o[f] = (f32x4){0.f, 0.f, 0.f, 0.f};

        for (int k0 = 0; k0 < 512; k0 += 32) {
            __syncthreads();
            const size_t yb = ybase + (size_t)(k0 + y2kb * 4) * 1024 + d0 + y2n4;
            const float4 v0 = *(const float4*)&y[yb];
            const float4 v1 = *(const float4*)&y[yb + 1024];
            const float4 v2 = *(const float4*)&y[yb + 2048];
            const float4 v3 = *(const float4*)&y[yb + 3072];
            const float rv[4][4] = {{v0.x, v0.y, v0.z, v0.w},
                                    {v1.x, v1.y, v1.z, v1.w},
                                    {v2.x, v2.y, v2.z, v2.w},
                                    {v3.x, v3.y, v3.z, v3.w}};
            #pragma unroll
            for (int j = 0; j < 4; ++j) {
                const bf16x4 h = (bf16x4){(__bf16)rv[0][j], (__bf16)rv[1][j],
                                          (__bf16)rv[2][j], (__bf16)rv[3][j]};
                *(bf16x4*)&Yh[y2n4 + j][y2kb * 4] = h;
            }
            __syncthreads();
            const bf16x8 a = *(const bf16x8*)&Pbuf[wave * 16 + ar][k0 + ak];
            #pragma unroll
            for (int f = 0; f < 8; ++f) {
                const bf16x8 bb = *(const bf16x8*)&Yh[f * 16 + ar][ak];
                o[f] = MFMA_BF16(a, bb, o[f]);
            }
        }
        #pragma unroll
        for (int f = 0; f < 8; ++f)
            #pragma unroll
            for (int r = 0; r < 4; ++r)
                out[pbase + (size_t)(wave * 16 + q * 4 + r) * 1024 + d0 + f * 16 + ar] = o[f][r];
    }
}

// ============================== launch ======================================

extern "C" void kernel_launch(void* const* d_in, const int* in_sizes, int n_in,
                              void* d_out, int out_size, void* d_ws, size_t ws_size,
                              hipStream_t stream) {
    (void)in_sizes; (void)n_in; (void)out_size;
    const float* x    = (const float*)d_in[0];
    const float* y    = (const float*)d_in[1];
    const float* W    = (const float*)d_in[2];
    const float* bias = (const float*)d_in[3];

    if (ws_size >= 268435456ULL) {
        _Float16* yf = (_Float16*)d_ws;
        _Float16* yT = yf + 33554432;
        _Float16* xh = yT + 33554432;
        _Float16* xl = xh + 33554432;
        _Float16* WT = xl + 33554432;
        const bool pre = ws_size >= 268435456ULL + 2097152ULL;

        prep_y_kernel<<<dim3(8192), dim3(256), 0, stream>>>(y, yf, yT);
        cvt_hl_kernel<<<dim3(2048), dim3(256), 0, stream>>>((const float4*)x, (f16x4*)xh,
                                                            (f16x4*)xl, 8388608);
        if (pre) {
            prep_w_kernel<<<dim3(256), dim3(256), 0, stream>>>(W, WT);
            proj_f16_kernel<true><<<dim3(2048), dim3(256), 0, stream>>>(xh, xl, WT, W, bias,
                                                                        (char*)d_out);
        } else {
            proj_f16_kernel<false><<<dim3(2048), dim3(256), 0, stream>>>(xh, xl, nullptr, W,
                                                                         bias, (char*)d_out);
        }
        attn_f16_kernel<<<dim3(512), dim3(256), 0, stream>>>(yf, yT, (char*)d_out);
    } else {
        float* out = (float*)d_out;
        proj_kernel_fb<<<dim3(256 * 8), dim3(256), 0, stream>>>(x, W, bias, out);
        attn_kernel_fb<<<dim3(64 * 8), dim3(256), 0, stream>>>(y, out);
    }
}